// Round 1
// baseline (183.444 us; speedup 1.0000x reference)
//
#include <hip/hip_runtime.h>

// corr: out[b, (di+4)*9+(dj+4), h, w] = sum_c x[b,c,h,w] * y[b,c,refl(h+di),refl(w+dj)]
// B=4, C=64, H=W=256, K=4 -> 81 displacement channels, reflect padding.

#define KRAD 4
#define DD   9          // 2K+1
#define ND   81         // DD*DD
#define CCH  64         // channels
#define HH   256
#define WW   256
#define TH   16
#define TW   16
#define CC   8          // channel chunk staged in LDS
#define HALO 24         // TH + 2*KRAD

__global__ __launch_bounds__(256, 4) void corr_hzp_kernel(
    const float* __restrict__ x, const float* __restrict__ y,
    float* __restrict__ out)
{
    __shared__ float ylds[CC * HALO * HALO];   // 8*576*4 = 18432 B

    const int tx = threadIdx.x & 15;
    const int ty = threadIdx.x >> 4;
    const int w0 = blockIdx.x * TW;
    const int h0 = blockIdx.y * TH;
    const int b  = blockIdx.z;

    const int h = h0 + ty;
    const int w = w0 + tx;

    float acc[ND];
#pragma unroll
    for (int d = 0; d < ND; ++d) acc[d] = 0.f;

    const size_t plane = (size_t)HH * WW;
    const size_t xpix  = (size_t)b * CCH * plane + (size_t)h * WW + w;
    const size_t ybat  = (size_t)b * CCH * plane;

    for (int c0 = 0; c0 < CCH; c0 += CC) {
        __syncthreads();   // protect previous chunk's reads
        // stage y[c0..c0+CC) halo tile (reflect-padded) into LDS
        for (int idx = threadIdx.x; idx < CC * HALO * HALO; idx += 256) {
            int cl  = idx / (HALO * HALO);
            int rem = idx - cl * (HALO * HALO);
            int r   = rem / HALO;
            int col = rem - r * HALO;
            int gh = h0 - KRAD + r;
            gh = gh < 0 ? -gh : (gh >= HH ? 2 * HH - 2 - gh : gh);
            int gw = w0 - KRAD + col;
            gw = gw < 0 ? -gw : (gw >= WW ? 2 * WW - 2 - gw : gw);
            ylds[idx] = y[ybat + (size_t)(c0 + cl) * plane + (size_t)gh * WW + gw];
        }
        __syncthreads();

        for (int cl = 0; cl < CC; ++cl) {
            const float xv = x[xpix + (size_t)(c0 + cl) * plane];
            const float* yp = &ylds[cl * (HALO * HALO) + ty * HALO + tx];
#pragma unroll
            for (int di = 0; di < DD; ++di) {
                const float* yr = yp + di * HALO;
#pragma unroll
                for (int dj = 0; dj < DD; ++dj) {
                    acc[di * DD + dj] = fmaf(xv, yr[dj], acc[di * DD + dj]);
                }
            }
        }
    }

    const size_t obase = (size_t)b * ND * plane + (size_t)h * WW + w;
#pragma unroll
    for (int d = 0; d < ND; ++d) {
        out[obase + (size_t)d * plane] = acc[d];
    }
}

extern "C" void kernel_launch(void* const* d_in, const int* in_sizes, int n_in,
                              void* d_out, int out_size, void* d_ws, size_t ws_size,
                              hipStream_t stream) {
    const float* x = (const float*)d_in[0];
    const float* y = (const float*)d_in[1];
    float* out = (float*)d_out;

    dim3 grid(WW / TW, HH / TH, 4);   // 16 x 16 x 4 = 1024 blocks
    dim3 block(256);
    corr_hzp_kernel<<<grid, block, 0, stream>>>(x, y, out);
}

// Round 2
// 96.870 us; speedup vs baseline: 1.8937x; 1.8937x over previous
//
#include <hip/hip_runtime.h>
#include <hip/hip_bf16.h>

// corr via MFMA band extraction:
// out[b,(di+4)*9+(dj+4),h,w] = sum_c x[b,c,h,w] * y[b,c,refl(h+di),refl(w+dj)]
// D[m,n] = sum_k A[m,k]B[k,n] with A = Y_bf16[w'-tile, c], B = X_bf16[c, w-tile]
// -> D[w',w] holds dj = w'-w diagonals; mask-store the 9 valid ones.

#define HH   256
#define WW   256
#define CCH  64
#define KRAD 4
#define ND   81

#define WT   16                 // output w per block
#define HT   32                 // output h per block
#define WY   24                 // staged y width = WT + 2*KRAD
#define RSTRIDE 144             // bytes per (row,p): 64 c * 2B + 16B pad (16B-aligned, uniform banks)
#define YRING 10
#define YSLOT (WY * RSTRIDE)    // 3456 B
#define XSLOT (WT * RSTRIDE)    // 2304 B

typedef __attribute__((ext_vector_type(8))) short bf16x8;
typedef __attribute__((ext_vector_type(4))) float f32x4;

__device__ __forceinline__ int reflect(int v, int n) {
    v = v < 0 ? -v : v;
    return v >= n ? 2 * n - 2 - v : v;
}
__device__ __forceinline__ unsigned f2bf_pk(float a, float b) {
    union { float f; unsigned u; } xa, xb;
    xa.f = a; xb.f = b;
    unsigned ra = (xa.u + 0x7fffu + ((xa.u >> 16) & 1u)) >> 16;
    unsigned rb = (xb.u + 0x7fffu + ((xb.u >> 16) & 1u)) >> 16;
    return ra | (rb << 16);
}

__global__ __launch_bounds__(256) void corr_mfma_kernel(
    const float* __restrict__ x, const float* __restrict__ y,
    float* __restrict__ out)
{
    __shared__ char lds[YRING * YSLOT + 2 * XSLOT];   // 34560 + 4608 = 39168 B
    char* ylds = lds;
    char* xlds = lds + YRING * YSLOT;

    const int t    = threadIdx.x;
    const int w0   = blockIdx.x * WT;
    const int h0   = blockIdx.y * HT;
    const int b    = blockIdx.z;
    const int wid  = t >> 6;
    const int lane = t & 63;
    const int lq   = lane >> 4;      // 0..3
    const int ln   = lane & 15;      // 0..15

    const size_t plane = (size_t)HH * WW;
    const float* yb = y + (size_t)b * CCH * plane;
    const float* xb = x + (size_t)b * CCH * plane;

    float yv[8];
    float xv[4];

    // ---- staging: load (global->reg) and write (reg->LDS) split ----
    const int yp  = t & 31;          // 0..31, active < WY
    const int ycg = t >> 5;          // 0..7 -> c = 8*ycg + j
    const int xp  = t & 15;          // 0..15
    const int xcg = t >> 4;          // 0..15 -> c = 4*xcg + j

    auto loadY = [&](int hrow) {
        int gh = reflect(hrow, HH);
        int pc = yp < WY ? yp : WY - 1;           // clamp idle lanes in-bounds
        int gw = reflect(w0 - KRAD + pc, WW);
        const float* src = yb + (size_t)(ycg * 8) * plane + (size_t)gh * WW + gw;
#pragma unroll
        for (int j = 0; j < 8; ++j) yv[j] = src[(size_t)j * plane];
    };
    auto writeY = [&](int slot) {
        if (yp < WY) {
            char* dst = ylds + slot * YSLOT + yp * RSTRIDE + ycg * 16;
#pragma unroll
            for (int m = 0; m < 4; ++m)
                *(unsigned*)(dst + 4 * m) = f2bf_pk(yv[2 * m], yv[2 * m + 1]);
        }
    };
    auto loadX = [&](int hrow) {
        int gh = reflect(hrow, HH);
        const float* src = xb + (size_t)(xcg * 4) * plane + (size_t)gh * WW + (w0 + xp);
#pragma unroll
        for (int j = 0; j < 4; ++j) xv[j] = src[(size_t)j * plane];
    };
    auto writeX = [&](int slot) {
        char* dst = xlds + slot * XSLOT + xp * RSTRIDE + xcg * 8;
#pragma unroll
        for (int m = 0; m < 2; ++m)
            *(unsigned*)(dst + 4 * m) = f2bf_pk(xv[2 * m], xv[2 * m + 1]);
    };

    // ---- prologue: Y rows h0-4 .. h0+4 -> slots 0..8 ; X row h0 -> slot 0 ----
#pragma unroll 1
    for (int j = 0; j < 9; ++j) {
        loadY(h0 - KRAD + j);
        writeY(j);
    }
    loadX(h0);
    writeX(0);
    __syncthreads();

    // ---- main loop over h ----
#pragma unroll 1
    for (int hh = 0; hh < HT; ++hh) {
        const int h = h0 + hh;

        // issue next-iteration global loads early (latency hides under MFMA phase)
        loadY(h + KRAD + 1);
        loadX(h + 1);

        // B fragments: X row h, both c-halves
        const char* xbase = xlds + (h & 1) * XSLOT + ln * RSTRIDE + lq * 16;
        bf16x8 bf0 = *(const bf16x8*)(xbase);
        bf16x8 bf1 = *(const bf16x8*)(xbase + 64);

        float* outb = out + (size_t)b * ND * plane + (size_t)h * WW + (w0 + ln);

        for (int dii = wid; dii < 9; dii += 4) {
            const int slot = (hh + dii) % YRING;
            const char* arow = ylds + slot * YSLOT + ln * RSTRIDE + lq * 16;
#pragma unroll
            for (int wt = 0; wt < 2; ++wt) {
                const char* ab = arow + wt * (16 * RSTRIDE);
                bf16x8 af0 = *(const bf16x8*)(ab);
                bf16x8 af1 = *(const bf16x8*)(ab + 64);
                f32x4 d = {0.f, 0.f, 0.f, 0.f};
                d = __builtin_amdgcn_mfma_f32_16x16x32_bf16(af0, bf0, d, 0, 0, 0);
                d = __builtin_amdgcn_mfma_f32_16x16x32_bf16(af1, bf1, d, 0, 0, 0);
#pragma unroll
                for (int r = 0; r < 4; ++r) {
                    int m  = lq * 4 + r;                       // D row (w' index)
                    int dj = (wt == 0) ? (m - ln - KRAD) : (m - ln + 12);
                    if (dj >= -KRAD && dj <= KRAD) {
                        int didx = dii * 9 + (dj + KRAD);
                        outb[(size_t)didx * plane] = d[r];
                    }
                }
            }
        }

        // write next-iteration tiles into LDS (disjoint slots from consumed ones)
        writeY((hh + 9) % YRING);
        writeX((h + 1) & 1);
        __syncthreads();
    }
}

extern "C" void kernel_launch(void* const* d_in, const int* in_sizes, int n_in,
                              void* d_out, int out_size, void* d_ws, size_t ws_size,
                              hipStream_t stream) {
    const float* x = (const float*)d_in[0];
    const float* y = (const float*)d_in[1];
    float* out = (float*)d_out;

    dim3 grid(WW / WT, HH / HT, 4);   // 16 x 8 x 4 = 512 blocks
    dim3 block(256);
    corr_mfma_kernel<<<grid, block, 0, stream>>>(x, y, out);
}